// Round 10
// baseline (321.316 us; speedup 1.0000x reference)
//
#include <hip/hip_runtime.h>
#include <hip/hip_bf16.h>
#include <math.h>

#define D_MODEL 768
#define N_HEADS 12
#define D_FF    3072
#define D_K     64
#define SEQ     2048
#define BATCH   2
#define M_TOK   (BATCH * SEQ)   // 4096 tokens
#define D_QKV   (3 * D_MODEL)   // 2304
#define BH      (BATCH * N_HEADS)

typedef __attribute__((ext_vector_type(8))) short short8;   // 8 x bf16 (4 VGPRs)
typedef __attribute__((ext_vector_type(4))) float f32x4;    // MFMA C/D

static __device__ __forceinline__ short f2bf(float f) {
    __hip_bfloat16 b = __float2bfloat16(f);
    return __builtin_bit_cast(short, b);
}

// tanh-form GELU
static __device__ __forceinline__ float gelu_f(float v) {
    const float u = 0.7978845608f * (v + 0.044715f * v * v * v);
    const float e = __expf(2.0f * u);
    const float t = 1.0f - 2.0f / (e + 1.0f);
    return 0.5f * v * (1.0f + t);
}

// async global->LDS, 16B/lane; lane i lands at ldsbase + i*16.
static __device__ __forceinline__ void load_lds16(const void* g, void* l) {
    __builtin_amdgcn_global_load_lds(
        (const __attribute__((address_space(1))) unsigned int*)g,
        (__attribute__((address_space(3))) unsigned int*)l,
        16, 0, 0);
}

// s_waitcnt immediate: vmcnt(N) only (expcnt=7, lgkmcnt=0xF untouched)
#define WAITCNT_VM(N) (0xF70 | (N))

// ---------------------------------------------------------------------------
// Merged prep kernel: 6 weight transposes + x cast + qkv bias pack.
// ---------------------------------------------------------------------------
__global__ __launch_bounds__(256) void prep_kernel(
    const float* __restrict__ x,  short* __restrict__ xb,
    const float* __restrict__ wq, const float* __restrict__ wk,
    const float* __restrict__ wv, short* __restrict__ wqkv_t,
    const float* __restrict__ wo, short* __restrict__ wo_t,
    const float* __restrict__ w1, short* __restrict__ w1_t,
    const float* __restrict__ w2, short* __restrict__ w2_t,
    const float* __restrict__ bq, const float* __restrict__ bk,
    const float* __restrict__ bv, float* __restrict__ bqkv)
{
    __shared__ float tile[32][33];
    const int bid = blockIdx.x;
    const int tid = threadIdx.x;

    if (bid < 6912) {
        const float* in; short* outp; int K, N, t;
        if (bid < 576)       { in = wq; outp = wqkv_t;              K = 768;  N = 768;  t = bid; }
        else if (bid < 1152) { in = wk; outp = wqkv_t + 589824;     K = 768;  N = 768;  t = bid - 576; }
        else if (bid < 1728) { in = wv; outp = wqkv_t + 2 * 589824; K = 768;  N = 768;  t = bid - 1152; }
        else if (bid < 2304) { in = wo; outp = wo_t;                K = 768;  N = 768;  t = bid - 1728; }
        else if (bid < 4608) { in = w1; outp = w1_t;                K = 768;  N = 3072; t = bid - 2304; }
        else                 { in = w2; outp = w2_t;                K = 3072; N = 768;  t = bid - 4608; }
        const int nb = N >> 5;
        const int bx = t % nb, by = t / nb;
        const int n0 = bx * 32, k0 = by * 32;
        const int tx = tid & 31, ty = tid >> 5;
#pragma unroll
        for (int i = 0; i < 32; i += 8)
            tile[ty + i][tx] = in[(size_t)(k0 + ty + i) * N + n0 + tx];
        __syncthreads();
#pragma unroll
        for (int i = 0; i < 32; i += 8)
            outp[(size_t)(n0 + ty + i) * K + k0 + tx] = f2bf(tile[tx][ty + i]);
    } else if (bid < 8448) {
        const int t = (bid - 6912) * 256 + tid;
        const float4 a = reinterpret_cast<const float4*>(x)[2 * t];
        const float4 b = reinterpret_cast<const float4*>(x)[2 * t + 1];
        short8 s;
        s[0] = f2bf(a.x); s[1] = f2bf(a.y); s[2] = f2bf(a.z); s[3] = f2bf(a.w);
        s[4] = f2bf(b.x); s[5] = f2bf(b.y); s[6] = f2bf(b.z); s[7] = f2bf(b.w);
        reinterpret_cast<short8*>(xb)[t] = s;
    } else {
        const int t = (bid - 8448) * 256 + tid;
        if (t < D_QKV)
            bqkv[t] = (t < 768) ? bq[t] : (t < 1536) ? bk[t - 768] : bv[t - 1536];
    }
}

// ---------------------------------------------------------------------------
// Unified bf16 MFMA GEMM: 128M x 64N tile, BK=64, XOR-swizzled LDS,
// TRIPLE-buffered, prefetch depth 2: tiles it+1 and it+2 stay in flight;
// per-iter wait is vmcnt(12) (tile it landed, 12 younger loads flying).
// 72 KB LDS -> 2 blocks/CU. 4 waves stacked in M.
// ---------------------------------------------------------------------------
#define EPI_QKV     0   // -> qb (scaled 0.125), kb, vtb (transposed)
#define EPI_GELU_BF 1   // bf16 out, tanh-gelu
#define EPI_RES_F32 2   // fp32 out, + res

template <int EPI>
__global__ __launch_bounds__(256) void gemm64(
    const short* __restrict__ A,    // [M][K] bf16
    const short* __restrict__ Bt,   // [N][K] bf16
    const float* __restrict__ bias, // [N]
    const float* __restrict__ res,  // [M][N] fp32 (EPI_RES_F32)
    void* __restrict__ Cout, void* __restrict__ Out2, void* __restrict__ Out3,
    int M, int N, int K)
{
    __shared__ short As[3][128 * 64];   // 48 KB
    __shared__ short Bs[3][64 * 64];    // 24 KB

    const int tid  = threadIdx.x;
    const int w    = tid >> 6;
    const int lane = tid & 63;
    const int m16  = lane & 15;
    const int quad = lane >> 4;
    const int bm = blockIdx.y * 128;
    const int bn = blockIdx.x * 64;

    const int l8 = lane >> 3;
    const int scol = ((lane & 7) ^ l8) * 8;   // swizzled source chunk
    const int rx = m16 & 7;

    auto stage = [&](int k0, int buf) {
#pragma unroll
        for (int i = 0; i < 4; ++i) {
            const int g = w * 4 + i;
            load_lds16(&A[(size_t)(bm + g * 8 + l8) * K + k0 + scol], &As[buf][g * 512]);
        }
#pragma unroll
        for (int i = 0; i < 2; ++i) {
            const int g = w * 2 + i;
            load_lds16(&Bt[(size_t)(bn + g * 8 + l8) * K + k0 + scol], &Bs[buf][g * 512]);
        }
    };

    f32x4 acc[2][4];
#pragma unroll
    for (int mt = 0; mt < 2; ++mt)
#pragma unroll
        for (int nt = 0; nt < 4; ++nt)
            acc[mt][nt] = (f32x4){0.f, 0.f, 0.f, 0.f};

    const int niter = K >> 6;
    stage(0, 0);
    if (niter > 1) stage(64, 1);

    for (int it = 0; it < niter; ++it) {
        const int cur = it % 3;
        __builtin_amdgcn_sched_barrier(0);
        __builtin_amdgcn_s_barrier();                 // (A) buf[(it+2)%3] reads done
        if (it + 2 < niter) {
            stage((it + 2) << 6, (it + 2) % 3);
            __builtin_amdgcn_s_waitcnt(WAITCNT_VM(12));   // tile it landed
        } else if (it + 1 < niter) {
            __builtin_amdgcn_s_waitcnt(WAITCNT_VM(6));
        } else {
            __builtin_amdgcn_s_waitcnt(WAITCNT_VM(0));
        }
        __builtin_amdgcn_s_barrier();                 // (B) all waves' tile landed
        __builtin_amdgcn_sched_barrier(0);
#pragma unroll
        for (int s = 0; s < 2; ++s) {
            const int cs = ((s * 4 + quad) ^ rx) * 8;
            short8 af[2], bf[4];
#pragma unroll
            for (int mt = 0; mt < 2; ++mt)
                af[mt] = *reinterpret_cast<const short8*>(
                    &As[cur][(w * 32 + mt * 16 + m16) * 64 + cs]);
#pragma unroll
            for (int nt = 0; nt < 4; ++nt)
                bf[nt] = *reinterpret_cast<const short8*>(
                    &Bs[cur][(nt * 16 + m16) * 64 + cs]);
#pragma unroll
            for (int mt = 0; mt < 2; ++mt)
#pragma unroll
                for (int nt = 0; nt < 4; ++nt)
                    acc[mt][nt] = __builtin_amdgcn_mfma_f32_16x16x32_bf16(
                        af[mt], bf[nt], acc[mt][nt], 0, 0, 0);
        }
    }

#pragma unroll
    for (int mt = 0; mt < 2; ++mt) {
#pragma unroll
        for (int r = 0; r < 4; ++r) {
            const int row = bm + w * 32 + mt * 16 + quad * 4 + r;
#pragma unroll
            for (int nt = 0; nt < 4; ++nt) {
                const int col = bn + nt * 16 + m16;
                float v = acc[mt][nt][r] + bias[col];
                if (EPI == EPI_QKV) {
                    const int b = row >> 11;
                    const int s = row & 2047;
                    const int sec = (col >= 1536) ? 2 : (col >= 768) ? 1 : 0;
                    const int cm = col - sec * 768;
                    const int h = cm >> 6;
                    const int d = cm & 63;
                    const int bh = b * N_HEADS + h;
                    if (sec == 0) {
                        ((short*)Cout)[((size_t)bh * SEQ + s) * 64 + d] = f2bf(v * 0.125f);
                    } else if (sec == 1) {
                        ((short*)Out2)[((size_t)bh * SEQ + s) * 64 + d] = f2bf(v);
                    } else {
                        ((short*)Out3)[((size_t)bh * 64 + d) * SEQ + s] = f2bf(v);
                    }
                } else if (EPI == EPI_GELU_BF) {
                    ((short*)Cout)[(size_t)row * N + col] = f2bf(gelu_f(v));
                } else {
                    v += res[(size_t)row * N + col];
                    ((float*)Cout)[(size_t)row * N + col] = v;
                }
            }
        }
    }
}

// ---------------------------------------------------------------------------
// Flash attention (round-8 version, known 62.7 us): KT=128, global_load_lds
// + XOR swizzle, plain __syncthreads, static-max softmax, l via MFMA-ones.
// ---------------------------------------------------------------------------
#define KT 128
#define PSTR 136

__global__ __launch_bounds__(256) void attn_mfma_kernel(
    const short* __restrict__ qb, const short* __restrict__ kb,
    const short* __restrict__ vtb, const int* __restrict__ mask,
    short* __restrict__ ctx)
{
    __shared__ short Klds[KT * 64];          // 16 KB
    __shared__ short Vtlds[D_K * KT];        // 16 KB
    __shared__ short Plds[4 * 16 * PSTR];    // 17.4 KB

    const int tid  = threadIdx.x;
    const int lane = tid & 63;
    const int wv   = tid >> 6;
    const int m16  = lane & 15;
    const int quad = lane >> 4;

    const int qtile = blockIdx.x * 64;
    const int bh = blockIdx.y;
    const int b = bh / N_HEADS;

    const size_t qrow = (size_t)bh * SEQ + qtile + wv * 16 + m16;
    short8 qf[2];
#pragma unroll
    for (int kc = 0; kc < 2; ++kc)
        qf[kc] = *reinterpret_cast<const short8*>(
            &qb[qrow * 64 + kc * 32 + quad * 8]);

    short8 ones;
#pragma unroll
    for (int i = 0; i < 8; ++i) ones[i] = (short)0x3F80;

    f32x4 o[4];
#pragma unroll
    for (int nt = 0; nt < 4; ++nt) o[nt] = (f32x4){0.f, 0.f, 0.f, 0.f};
    f32x4 lacc = (f32x4){0.f, 0.f, 0.f, 0.f};

    const int* mrow = mask + (size_t)b * SEQ;

    const int l8 = lane >> 3;
    const int kcol = ((lane & 7) ^ l8) * 8;
    const int l16 = lane >> 4;
    const int c16 = lane & 15;
    const int rx8 = m16 & 7;

    for (int kt0 = 0; kt0 < SEQ; kt0 += KT) {
        __syncthreads();
#pragma unroll
        for (int i = 0; i < 4; ++i) {
            const int g = wv * 4 + i;
            const int row = g * 8 + l8;
            load_lds16(&kb[((size_t)bh * SEQ + kt0 + row) * 64 + kcol], &Klds[g * 512]);
        }
#pragma unroll
        for (int i = 0; i < 4; ++i) {
            const int g = wv * 4 + i;
            const int row = g * 4 + l16;
            const int vcol = (c16 ^ (row & 15)) * 8;
            load_lds16(&vtb[((size_t)bh * 64 + row) * SEQ + kt0 + vcol], &Vtlds[g * 512]);
        }
        __syncthreads();

        f32x4 s[8];
#pragma unroll
        for (int nt = 0; nt < 8; ++nt) s[nt] = (f32x4){0.f, 0.f, 0.f, 0.f};
#pragma unroll
        for (int nt = 0; nt < 8; ++nt) {
#pragma unroll
            for (int kc = 0; kc < 2; ++kc) {
                const short8 kf = *reinterpret_cast<const short8*>(
                    &Klds[(nt * 16 + m16) * 64 + (((kc * 4 + quad) ^ rx8) * 8)]);
                s[nt] = __builtin_amdgcn_mfma_f32_16x16x32_bf16(qf[kc], kf, s[nt], 0, 0, 0);
            }
        }

        short* Pw = &Plds[wv * 16 * PSTR];
#pragma unroll
        for (int nt = 0; nt < 8; ++nt) {
            const int mk = mrow[kt0 + nt * 16 + m16];
#pragma unroll
            for (int r = 0; r < 4; ++r) {
                const float sv = (mk == 0) ? -1e9f : fminf(s[nt][r], 30.f);
                Pw[(quad * 4 + r) * PSTR + nt * 16 + m16] = f2bf(__expf(sv));
            }
        }

#pragma unroll
        for (int kc = 0; kc < 4; ++kc) {
            const short8 af = *reinterpret_cast<const short8*>(
                &Pw[m16 * PSTR + kc * 32 + quad * 8]);
#pragma unroll
            for (int nt = 0; nt < 4; ++nt) {
                const short8 bf = *reinterpret_cast<const short8*>(
                    &Vtlds[(nt * 16 + m16) * KT + (((kc * 4 + quad) ^ m16) * 8)]);
                o[nt] = __builtin_amdgcn_mfma_f32_16x16x32_bf16(af, bf, o[nt], 0, 0, 0);
            }
            lacc = __builtin_amdgcn_mfma_f32_16x16x32_bf16(af, ones, lacc, 0, 0, 0);
        }
    }

    const int h = bh % N_HEADS;
#pragma unroll
    for (int r = 0; r < 4; ++r) {
        const float inv_l = 1.0f / lacc[r];
        const size_t row = (size_t)(b * SEQ + qtile + wv * 16 + quad * 4 + r);
#pragma unroll
        for (int nt = 0; nt < 4; ++nt)
            ctx[row * D_MODEL + h * D_K + nt * 16 + m16] = f2bf(o[nt][r] * inv_l);
    }
}

// ---------------------------------------------------------------------------
// LayerNorm over last dim (768). One block (256 threads) per row.
// ---------------------------------------------------------------------------
template <bool DUAL>
__global__ __launch_bounds__(256) void layernorm_kernel(
    const float* __restrict__ in, const float* __restrict__ g,
    const float* __restrict__ be, float* __restrict__ outf,
    short* __restrict__ outb)
{
    const int row = blockIdx.x;
    const float* x = in + (size_t)row * D_MODEL;

    float s = 0.0f, s2 = 0.0f;
    for (int i = threadIdx.x; i < D_MODEL; i += 256) {
        const float v = x[i];
        s += v; s2 += v * v;
    }
#pragma unroll
    for (int off = 32; off > 0; off >>= 1) {
        s  += __shfl_down(s, off);
        s2 += __shfl_down(s2, off);
    }
    __shared__ float red[2][4];
    const int wid = threadIdx.x >> 6;
    const int lane = threadIdx.x & 63;
    if (lane == 0) { red[0][wid] = s; red[1][wid] = s2; }
    __syncthreads();
    __shared__ float stats[2];
    if (threadIdx.x == 0) {
        float ts = 0.0f, ts2 = 0.0f;
#pragma unroll
        for (int w = 0; w < 4; ++w) { ts += red[0][w]; ts2 += red[1][w]; }
        const float mu = ts * (1.0f / D_MODEL);
        const float var = ts2 * (1.0f / D_MODEL) - mu * mu;
        stats[0] = mu;
        stats[1] = rsqrtf(var + 1e-5f);
    }
    __syncthreads();
    const float mu = stats[0], rstd = stats[1];
    for (int i = threadIdx.x; i < D_MODEL; i += 256) {
        const float v = (x[i] - mu) * rstd * g[i] + be[i];
        outf[(size_t)row * D_MODEL + i] = v;
        if (DUAL) outb[(size_t)row * D_MODEL + i] = f2bf(v);
    }
}

// ---------------------------------------------------------------------------
extern "C" void kernel_launch(void* const* d_in, const int* in_sizes, int n_in,
                              void* d_out, int out_size, void* d_ws, size_t ws_size,
                              hipStream_t stream)
{
    const float* x    = (const float*)d_in[0];
    const int*   mask = (const int*)  d_in[1];
    const float* wq   = (const float*)d_in[2];
    const float* bq   = (const float*)d_in[3];
    const float* wk   = (const float*)d_in[4];
    const float* bk   = (const float*)d_in[5];
    const float* wv   = (const float*)d_in[6];
    const float* bv   = (const float*)d_in[7];
    const float* wo   = (const float*)d_in[8];
    const float* bo   = (const float*)d_in[9];
    const float* w1   = (const float*)d_in[10];
    const float* b1   = (const float*)d_in[11];
    const float* w2   = (const float*)d_in[12];
    const float* b2   = (const float*)d_in[13];
    const float* g1   = (const float*)d_in[14];
    const float* be1  = (const float*)d_in[15];
    const float* g2   = (const float*)d_in[16];
    const float* be2  = (const float*)d_in[17];

    float* out = (float*)d_out;

    char* cur = (char*)d_ws;
    auto alloc = [&](size_t bytes) { char* p = cur; cur += (bytes + 255) & ~(size_t)255; return p; };

    short* xb      = (short*)alloc((size_t)M_TOK * D_MODEL * 2);
    short* qbuf    = (short*)alloc((size_t)BH * SEQ * D_K * 2);
    short* kbuf    = (short*)alloc((size_t)BH * SEQ * D_K * 2);
    short* vtbuf   = (short*)alloc((size_t)BH * D_K * SEQ * 2);
    short* ctxb    = (short*)alloc((size_t)M_TOK * D_MODEL * 2);
    short* x1b     = (short*)alloc((size_t)M_TOK * D_MODEL * 2);
    short* ffb     = (short*)alloc((size_t)M_TOK * D_FF * 2);
    short* wqkv_t  = (short*)alloc((size_t)D_QKV * D_MODEL * 2);
    short* wo_t    = (short*)alloc((size_t)D_MODEL * D_MODEL * 2);
    short* w1_t    = (short*)alloc((size_t)D_FF * D_MODEL * 2);
    short* w2_t    = (short*)alloc((size_t)D_MODEL * D_FF * 2);
    float* bqkv    = (float*)alloc((size_t)D_QKV * 4);
    float* h1      = (float*)alloc((size_t)M_TOK * D_MODEL * 4);
    float* x1f     = (float*)alloc((size_t)M_TOK * D_MODEL * 4);
    float* h2      = (float*)alloc((size_t)M_TOK * D_MODEL * 4);

    const dim3 blk(256);

    // ---- prep (single launch) ----
    hipLaunchKernelGGL(prep_kernel, dim3(8457), blk, 0, stream,
                       x, xb, wq, wk, wv, wqkv_t, wo, wo_t,
                       w1, w1_t, w2, w2_t, bq, bk, bv, bqkv);

    // ---- fused QKV GEMM -> qb/kb/vtb (1152 blocks) ----
    hipLaunchKernelGGL((gemm64<EPI_QKV>), dim3(D_QKV / 64, M_TOK / 128), blk, 0, stream,
                       xb, wqkv_t, bqkv, nullptr, qbuf, kbuf, vtbuf, M_TOK, D_QKV, D_MODEL);

    // ---- flash attention (round-8 version) ----
    hipLaunchKernelGGL(attn_mfma_kernel, dim3(SEQ / 64, BH), blk, 0, stream,
                       qbuf, kbuf, vtbuf, mask, ctxb);

    // ---- Wo projection + residual -> fp32 h1 ----
    hipLaunchKernelGGL((gemm64<EPI_RES_F32>), dim3(D_MODEL / 64, M_TOK / 128), blk, 0, stream,
                       ctxb, wo_t, bo, x, h1, nullptr, nullptr, M_TOK, D_MODEL, D_MODEL);

    // ---- LN1 -> fp32 x1f + bf16 x1b ----
    hipLaunchKernelGGL((layernorm_kernel<true>), dim3(M_TOK), blk, 0, stream,
                       h1, g1, be1, x1f, x1b);

    // ---- FF1 + GELU -> bf16 ff (1536 blocks) ----
    hipLaunchKernelGGL((gemm64<EPI_GELU_BF>), dim3(D_FF / 64, M_TOK / 128), blk, 0, stream,
                       x1b, w1_t, b1, nullptr, ffb, nullptr, nullptr, M_TOK, D_FF, D_MODEL);

    // ---- FF2 + residual -> fp32 h2 ----
    hipLaunchKernelGGL((gemm64<EPI_RES_F32>), dim3(D_MODEL / 64, M_TOK / 128), blk, 0, stream,
                       ffb, w2_t, b2, x1f, h2, nullptr, nullptr, M_TOK, D_MODEL, D_FF);

    // ---- LN2 -> out ----
    hipLaunchKernelGGL((layernorm_kernel<false>), dim3(M_TOK), blk, 0, stream,
                       h2, g2, be2, out, nullptr);
}

// Round 11
// 305.781 us; speedup vs baseline: 1.0508x; 1.0508x over previous
//
#include <hip/hip_runtime.h>
#include <hip/hip_bf16.h>
#include <math.h>

#define D_MODEL 768
#define N_HEADS 12
#define D_FF    3072
#define D_K     64
#define SEQ     2048
#define BATCH   2
#define M_TOK   (BATCH * SEQ)   // 4096 tokens
#define D_QKV   (3 * D_MODEL)   // 2304
#define BH      (BATCH * N_HEADS)

typedef __attribute__((ext_vector_type(8))) short short8;   // 8 x bf16 (4 VGPRs)
typedef __attribute__((ext_vector_type(4))) float f32x4;    // MFMA C/D

static __device__ __forceinline__ short f2bf(float f) {
    __hip_bfloat16 b = __float2bfloat16(f);
    return __builtin_bit_cast(short, b);
}

// tanh-form GELU
static __device__ __forceinline__ float gelu_f(float v) {
    const float u = 0.7978845608f * (v + 0.044715f * v * v * v);
    const float e = __expf(2.0f * u);
    const float t = 1.0f - 2.0f / (e + 1.0f);
    return 0.5f * v * (1.0f + t);
}

// async global->LDS, 16B/lane; lane i lands at ldsbase + i*16.
static __device__ __forceinline__ void load_lds16(const void* g, void* l) {
    __builtin_amdgcn_global_load_lds(
        (const __attribute__((address_space(1))) unsigned int*)g,
        (__attribute__((address_space(3))) unsigned int*)l,
        16, 0, 0);
}

// s_waitcnt immediate: vmcnt(N) only (expcnt=7, lgkmcnt=0xF untouched)
#define WAITCNT_VM(N) (0xF70 | (N))

// ---------------------------------------------------------------------------
// Merged prep kernel: 6 weight transposes + x cast + qkv bias pack.
// ---------------------------------------------------------------------------
__global__ __launch_bounds__(256) void prep_kernel(
    const float* __restrict__ x,  short* __restrict__ xb,
    const float* __restrict__ wq, const float* __restrict__ wk,
    const float* __restrict__ wv, short* __restrict__ wqkv_t,
    const float* __restrict__ wo, short* __restrict__ wo_t,
    const float* __restrict__ w1, short* __restrict__ w1_t,
    const float* __restrict__ w2, short* __restrict__ w2_t,
    const float* __restrict__ bq, const float* __restrict__ bk,
    const float* __restrict__ bv, float* __restrict__ bqkv)
{
    __shared__ float tile[32][33];
    const int bid = blockIdx.x;
    const int tid = threadIdx.x;

    if (bid < 6912) {
        const float* in; short* outp; int K, N, t;
        if (bid < 576)       { in = wq; outp = wqkv_t;              K = 768;  N = 768;  t = bid; }
        else if (bid < 1152) { in = wk; outp = wqkv_t + 589824;     K = 768;  N = 768;  t = bid - 576; }
        else if (bid < 1728) { in = wv; outp = wqkv_t + 2 * 589824; K = 768;  N = 768;  t = bid - 1152; }
        else if (bid < 2304) { in = wo; outp = wo_t;                K = 768;  N = 768;  t = bid - 1728; }
        else if (bid < 4608) { in = w1; outp = w1_t;                K = 768;  N = 3072; t = bid - 2304; }
        else                 { in = w2; outp = w2_t;                K = 3072; N = 768;  t = bid - 4608; }
        const int nb = N >> 5;
        const int bx = t % nb, by = t / nb;
        const int n0 = bx * 32, k0 = by * 32;
        const int tx = tid & 31, ty = tid >> 5;
#pragma unroll
        for (int i = 0; i < 32; i += 8)
            tile[ty + i][tx] = in[(size_t)(k0 + ty + i) * N + n0 + tx];
        __syncthreads();
#pragma unroll
        for (int i = 0; i < 32; i += 8)
            outp[(size_t)(n0 + ty + i) * K + k0 + tx] = f2bf(tile[tx][ty + i]);
    } else if (bid < 8448) {
        const int t = (bid - 6912) * 256 + tid;
        const float4 a = reinterpret_cast<const float4*>(x)[2 * t];
        const float4 b = reinterpret_cast<const float4*>(x)[2 * t + 1];
        short8 s;
        s[0] = f2bf(a.x); s[1] = f2bf(a.y); s[2] = f2bf(a.z); s[3] = f2bf(a.w);
        s[4] = f2bf(b.x); s[5] = f2bf(b.y); s[6] = f2bf(b.z); s[7] = f2bf(b.w);
        reinterpret_cast<short8*>(xb)[t] = s;
    } else {
        const int t = (bid - 8448) * 256 + tid;
        if (t < D_QKV)
            bqkv[t] = (t < 768) ? bq[t] : (t < 1536) ? bk[t - 768] : bv[t - 1536];
    }
}

// ---------------------------------------------------------------------------
// Unified bf16 MFMA GEMM: 128M x 64N tile, BK=64, XOR-swizzled LDS,
// double-buffered with raw s_barrier + s_waitcnt vmcnt(6) (round-9 proven
// config: 48 KB LDS -> 3 blocks/CU). XCD-aware block swizzle: linear id % 8
// (presumed round-robin XCD) owns a contiguous 4-block M-slice, so each
// XCD's L2 holds a ~768 KB A-slice and weight tiles get tight temporal reuse.
// ---------------------------------------------------------------------------
#define EPI_QKV     0   // -> qb (scaled 0.125), kb, vtb (transposed)
#define EPI_GELU_BF 1   // bf16 out, tanh-gelu
#define EPI_RES_F32 2   // fp32 out, + res

template <int EPI>
__global__ __launch_bounds__(256) void gemm64(
    const short* __restrict__ A,    // [M][K] bf16
    const short* __restrict__ Bt,   // [N][K] bf16
    const float* __restrict__ bias, // [N]
    const float* __restrict__ res,  // [M][N] fp32 (EPI_RES_F32)
    void* __restrict__ Cout, void* __restrict__ Out2, void* __restrict__ Out3,
    int M, int N, int K)
{
    __shared__ short As[2][128 * 64];   // 32 KB
    __shared__ short Bs[2][64 * 64];    // 16 KB

    const int tid  = threadIdx.x;
    const int w    = tid >> 6;
    const int lane = tid & 63;
    const int m16  = lane & 15;
    const int quad = lane >> 4;

    // XCD/L2 block swizzle (nby must be divisible by 8; ours is 32)
    const int nbx = gridDim.x;
    const int id  = blockIdx.y * nbx + blockIdx.x;
    const int xcd = id & 7;
    const int j   = id >> 3;
    const int nbyg = gridDim.y >> 3;            // 4
    const int by = xcd * nbyg + (j % nbyg);
    const int bx = j / nbyg;
    const int bm = by * 128;
    const int bn = bx * 64;

    const int l8 = lane >> 3;
    const int scol = ((lane & 7) ^ l8) * 8;   // swizzled source chunk
    const int rx = m16 & 7;

    auto stage = [&](int k0, int buf) {
#pragma unroll
        for (int i = 0; i < 4; ++i) {
            const int g = w * 4 + i;
            load_lds16(&A[(size_t)(bm + g * 8 + l8) * K + k0 + scol], &As[buf][g * 512]);
        }
#pragma unroll
        for (int i = 0; i < 2; ++i) {
            const int g = w * 2 + i;
            load_lds16(&Bt[(size_t)(bn + g * 8 + l8) * K + k0 + scol], &Bs[buf][g * 512]);
        }
    };

    f32x4 acc[2][4];
#pragma unroll
    for (int mt = 0; mt < 2; ++mt)
#pragma unroll
        for (int nt = 0; nt < 4; ++nt)
            acc[mt][nt] = (f32x4){0.f, 0.f, 0.f, 0.f};

    const int niter = K >> 6;
    stage(0, 0);

    for (int it = 0; it < niter; ++it) {
        const int cur = it & 1;
        __builtin_amdgcn_sched_barrier(0);
        __builtin_amdgcn_s_barrier();                 // (A) prev buf reads done
        if (it + 1 < niter) {
            stage((it + 1) << 6, cur ^ 1);
            __builtin_amdgcn_s_waitcnt(WAITCNT_VM(6));
        } else {
            __builtin_amdgcn_s_waitcnt(WAITCNT_VM(0));
        }
        __builtin_amdgcn_s_barrier();                 // (B) tile it landed
        __builtin_amdgcn_sched_barrier(0);
#pragma unroll
        for (int s = 0; s < 2; ++s) {
            const int cs = ((s * 4 + quad) ^ rx) * 8;
            short8 af[2], bf[4];
#pragma unroll
            for (int mt = 0; mt < 2; ++mt)
                af[mt] = *reinterpret_cast<const short8*>(
                    &As[cur][(w * 32 + mt * 16 + m16) * 64 + cs]);
#pragma unroll
            for (int nt = 0; nt < 4; ++nt)
                bf[nt] = *reinterpret_cast<const short8*>(
                    &Bs[cur][(nt * 16 + m16) * 64 + cs]);
#pragma unroll
            for (int mt = 0; mt < 2; ++mt)
#pragma unroll
                for (int nt = 0; nt < 4; ++nt)
                    acc[mt][nt] = __builtin_amdgcn_mfma_f32_16x16x32_bf16(
                        af[mt], bf[nt], acc[mt][nt], 0, 0, 0);
        }
    }

#pragma unroll
    for (int mt = 0; mt < 2; ++mt) {
#pragma unroll
        for (int r = 0; r < 4; ++r) {
            const int row = bm + w * 32 + mt * 16 + quad * 4 + r;
#pragma unroll
            for (int nt = 0; nt < 4; ++nt) {
                const int col = bn + nt * 16 + m16;
                float v = acc[mt][nt][r] + bias[col];
                if (EPI == EPI_QKV) {
                    const int b = row >> 11;
                    const int s = row & 2047;
                    const int sec = (col >= 1536) ? 2 : (col >= 768) ? 1 : 0;
                    const int cm = col - sec * 768;
                    const int h = cm >> 6;
                    const int d = cm & 63;
                    const int bh = b * N_HEADS + h;
                    if (sec == 0) {
                        ((short*)Cout)[((size_t)bh * SEQ + s) * 64 + d] = f2bf(v * 0.125f);
                    } else if (sec == 1) {
                        ((short*)Out2)[((size_t)bh * SEQ + s) * 64 + d] = f2bf(v);
                    } else {
                        ((short*)Out3)[((size_t)bh * 64 + d) * SEQ + s] = f2bf(v);
                    }
                } else if (EPI == EPI_GELU_BF) {
                    ((short*)Cout)[(size_t)row * N + col] = f2bf(gelu_f(v));
                } else {
                    v += res[(size_t)row * N + col];
                    ((float*)Cout)[(size_t)row * N + col] = v;
                }
            }
        }
    }
}

// ---------------------------------------------------------------------------
// Flash attention (round-8 version, 62.6 us): KT=128, global_load_lds + XOR
// swizzle, plain __syncthreads, static-max softmax, l via MFMA-ones.
// ---------------------------------------------------------------------------
#define KT 128
#define PSTR 136

__global__ __launch_bounds__(256) void attn_mfma_kernel(
    const short* __restrict__ qb, const short* __restrict__ kb,
    const short* __restrict__ vtb, const int* __restrict__ mask,
    short* __restrict__ ctx)
{
    __shared__ short Klds[KT * 64];          // 16 KB
    __shared__ short Vtlds[D_K * KT];        // 16 KB
    __shared__ short Plds[4 * 16 * PSTR];    // 17.4 KB

    const int tid  = threadIdx.x;
    const int lane = tid & 63;
    const int wv   = tid >> 6;
    const int m16  = lane & 15;
    const int quad = lane >> 4;

    const int qtile = blockIdx.x * 64;
    const int bh = blockIdx.y;
    const int b = bh / N_HEADS;

    const size_t qrow = (size_t)bh * SEQ + qtile + wv * 16 + m16;
    short8 qf[2];
#pragma unroll
    for (int kc = 0; kc < 2; ++kc)
        qf[kc] = *reinterpret_cast<const short8*>(
            &qb[qrow * 64 + kc * 32 + quad * 8]);

    short8 ones;
#pragma unroll
    for (int i = 0; i < 8; ++i) ones[i] = (short)0x3F80;

    f32x4 o[4];
#pragma unroll
    for (int nt = 0; nt < 4; ++nt) o[nt] = (f32x4){0.f, 0.f, 0.f, 0.f};
    f32x4 lacc = (f32x4){0.f, 0.f, 0.f, 0.f};

    const int* mrow = mask + (size_t)b * SEQ;

    const int l8 = lane >> 3;
    const int kcol = ((lane & 7) ^ l8) * 8;
    const int l16 = lane >> 4;
    const int c16 = lane & 15;
    const int rx8 = m16 & 7;

    for (int kt0 = 0; kt0 < SEQ; kt0 += KT) {
        __syncthreads();
#pragma unroll
        for (int i = 0; i < 4; ++i) {
            const int g = wv * 4 + i;
            const int row = g * 8 + l8;
            load_lds16(&kb[((size_t)bh * SEQ + kt0 + row) * 64 + kcol], &Klds[g * 512]);
        }
#pragma unroll
        for (int i = 0; i < 4; ++i) {
            const int g = wv * 4 + i;
            const int row = g * 4 + l16;
            const int vcol = (c16 ^ (row & 15)) * 8;
            load_lds16(&vtb[((size_t)bh * 64 + row) * SEQ + kt0 + vcol], &Vtlds[g * 512]);
        }
        __syncthreads();

        f32x4 s[8];
#pragma unroll
        for (int nt = 0; nt < 8; ++nt) s[nt] = (f32x4){0.f, 0.f, 0.f, 0.f};
#pragma unroll
        for (int nt = 0; nt < 8; ++nt) {
#pragma unroll
            for (int kc = 0; kc < 2; ++kc) {
                const short8 kf = *reinterpret_cast<const short8*>(
                    &Klds[(nt * 16 + m16) * 64 + (((kc * 4 + quad) ^ rx8) * 8)]);
                s[nt] = __builtin_amdgcn_mfma_f32_16x16x32_bf16(qf[kc], kf, s[nt], 0, 0, 0);
            }
        }

        short* Pw = &Plds[wv * 16 * PSTR];
#pragma unroll
        for (int nt = 0; nt < 8; ++nt) {
            const int mk = mrow[kt0 + nt * 16 + m16];
#pragma unroll
            for (int r = 0; r < 4; ++r) {
                const float sv = (mk == 0) ? -1e9f : fminf(s[nt][r], 30.f);
                Pw[(quad * 4 + r) * PSTR + nt * 16 + m16] = f2bf(__expf(sv));
            }
        }

#pragma unroll
        for (int kc = 0; kc < 4; ++kc) {
            const short8 af = *reinterpret_cast<const short8*>(
                &Pw[m16 * PSTR + kc * 32 + quad * 8]);
#pragma unroll
            for (int nt = 0; nt < 4; ++nt) {
                const short8 bf = *reinterpret_cast<const short8*>(
                    &Vtlds[(nt * 16 + m16) * KT + (((kc * 4 + quad) ^ m16) * 8)]);
                o[nt] = __builtin_amdgcn_mfma_f32_16x16x32_bf16(af, bf, o[nt], 0, 0, 0);
            }
            lacc = __builtin_amdgcn_mfma_f32_16x16x32_bf16(af, ones, lacc, 0, 0, 0);
        }
    }

    const int h = bh % N_HEADS;
#pragma unroll
    for (int r = 0; r < 4; ++r) {
        const float inv_l = 1.0f / lacc[r];
        const size_t row = (size_t)(b * SEQ + qtile + wv * 16 + quad * 4 + r);
#pragma unroll
        for (int nt = 0; nt < 4; ++nt)
            ctx[row * D_MODEL + h * D_K + nt * 16 + m16] = f2bf(o[nt][r] * inv_l);
    }
}

// ---------------------------------------------------------------------------
// LayerNorm over last dim (768). One block (256 threads) per row.
// ---------------------------------------------------------------------------
template <bool DUAL>
__global__ __launch_bounds__(256) void layernorm_kernel(
    const float* __restrict__ in, const float* __restrict__ g,
    const float* __restrict__ be, float* __restrict__ outf,
    short* __restrict__ outb)
{
    const int row = blockIdx.x;
    const float* x = in + (size_t)row * D_MODEL;

    float s = 0.0f, s2 = 0.0f;
    for (int i = threadIdx.x; i < D_MODEL; i += 256) {
        const float v = x[i];
        s += v; s2 += v * v;
    }
#pragma unroll
    for (int off = 32; off > 0; off >>= 1) {
        s  += __shfl_down(s, off);
        s2 += __shfl_down(s2, off);
    }
    __shared__ float red[2][4];
    const int wid = threadIdx.x >> 6;
    const int lane = threadIdx.x & 63;
    if (lane == 0) { red[0][wid] = s; red[1][wid] = s2; }
    __syncthreads();
    __shared__ float stats[2];
    if (threadIdx.x == 0) {
        float ts = 0.0f, ts2 = 0.0f;
#pragma unroll
        for (int w = 0; w < 4; ++w) { ts += red[0][w]; ts2 += red[1][w]; }
        const float mu = ts * (1.0f / D_MODEL);
        const float var = ts2 * (1.0f / D_MODEL) - mu * mu;
        stats[0] = mu;
        stats[1] = rsqrtf(var + 1e-5f);
    }
    __syncthreads();
    const float mu = stats[0], rstd = stats[1];
    for (int i = threadIdx.x; i < D_MODEL; i += 256) {
        const float v = (x[i] - mu) * rstd * g[i] + be[i];
        outf[(size_t)row * D_MODEL + i] = v;
        if (DUAL) outb[(size_t)row * D_MODEL + i] = f2bf(v);
    }
}

// ---------------------------------------------------------------------------
extern "C" void kernel_launch(void* const* d_in, const int* in_sizes, int n_in,
                              void* d_out, int out_size, void* d_ws, size_t ws_size,
                              hipStream_t stream)
{
    const float* x    = (const float*)d_in[0];
    const int*   mask = (const int*)  d_in[1];
    const float* wq   = (const float*)d_in[2];
    const float* bq   = (const float*)d_in[3];
    const float* wk   = (const float*)d_in[4];
    const float* bk   = (const float*)d_in[5];
    const float* wv   = (const float*)d_in[6];
    const float* bv   = (const float*)d_in[7];
    const float* wo   = (const float*)d_in[8];
    const float* bo   = (const float*)d_in[9];
    const float* w1   = (const float*)d_in[10];
    const float* b1   = (const float*)d_in[11];
    const float* w2   = (const float*)d_in[12];
    const float* b2   = (const float*)d_in[13];
    const float* g1   = (const float*)d_in[14];
    const float* be1  = (const float*)d_in[15];
    const float* g2   = (const float*)d_in[16];
    const float* be2  = (const float*)d_in[17];

    float* out = (float*)d_out;

    char* cur = (char*)d_ws;
    auto alloc = [&](size_t bytes) { char* p = cur; cur += (bytes + 255) & ~(size_t)255; return p; };

    short* xb      = (short*)alloc((size_t)M_TOK * D_MODEL * 2);
    short* qbuf    = (short*)alloc((size_t)BH * SEQ * D_K * 2);
    short* kbuf    = (short*)alloc((size_t)BH * SEQ * D_K * 2);
    short* vtbuf   = (short*)alloc((size_t)BH * D_K * SEQ * 2);
    short* ctxb    = (short*)alloc((size_t)M_TOK * D_MODEL * 2);
    short* x1b     = (short*)alloc((size_t)M_TOK * D_MODEL * 2);
    short* ffb     = (short*)alloc((size_t)M_TOK * D_FF * 2);
    short* wqkv_t  = (short*)alloc((size_t)D_QKV * D_MODEL * 2);
    short* wo_t    = (short*)alloc((size_t)D_MODEL * D_MODEL * 2);
    short* w1_t    = (short*)alloc((size_t)D_FF * D_MODEL * 2);
    short* w2_t    = (short*)alloc((size_t)D_MODEL * D_FF * 2);
    float* bqkv    = (float*)alloc((size_t)D_QKV * 4);
    float* h1      = (float*)alloc((size_t)M_TOK * D_MODEL * 4);
    float* x1f     = (float*)alloc((size_t)M_TOK * D_MODEL * 4);
    float* h2      = (float*)alloc((size_t)M_TOK * D_MODEL * 4);

    const dim3 blk(256);

    // ---- prep (single launch) ----
    hipLaunchKernelGGL(prep_kernel, dim3(8457), blk, 0, stream,
                       x, xb, wq, wk, wv, wqkv_t, wo, wo_t,
                       w1, w1_t, w2, w2_t, bq, bk, bv, bqkv);

    // ---- fused QKV GEMM -> qb/kb/vtb (1152 blocks) ----
    hipLaunchKernelGGL((gemm64<EPI_QKV>), dim3(D_QKV / 64, M_TOK / 128), blk, 0, stream,
                       xb, wqkv_t, bqkv, nullptr, qbuf, kbuf, vtbuf, M_TOK, D_QKV, D_MODEL);

    // ---- flash attention ----
    hipLaunchKernelGGL(attn_mfma_kernel, dim3(SEQ / 64, BH), blk, 0, stream,
                       qbuf, kbuf, vtbuf, mask, ctxb);

    // ---- Wo projection + residual -> fp32 h1 ----
    hipLaunchKernelGGL((gemm64<EPI_RES_F32>), dim3(D_MODEL / 64, M_TOK / 128), blk, 0, stream,
                       ctxb, wo_t, bo, x, h1, nullptr, nullptr, M_TOK, D_MODEL, D_MODEL);

    // ---- LN1 -> fp32 x1f + bf16 x1b ----
    hipLaunchKernelGGL((layernorm_kernel<true>), dim3(M_TOK), blk, 0, stream,
                       h1, g1, be1, x1f, x1b);

    // ---- FF1 + GELU -> bf16 ff (1536 blocks) ----
    hipLaunchKernelGGL((gemm64<EPI_GELU_BF>), dim3(D_FF / 64, M_TOK / 128), blk, 0, stream,
                       x1b, w1_t, b1, nullptr, ffb, nullptr, nullptr, M_TOK, D_FF, D_MODEL);

    // ---- FF2 + residual -> fp32 h2 ----
    hipLaunchKernelGGL((gemm64<EPI_RES_F32>), dim3(D_MODEL / 64, M_TOK / 128), blk, 0, stream,
                       ffb, w2_t, b2, x1f, h2, nullptr, nullptr, M_TOK, D_MODEL, D_FF);

    // ---- LN2 -> out ----
    hipLaunchKernelGGL((layernorm_kernel<false>), dim3(M_TOK), blk, 0, stream,
                       h2, g2, be2, out, nullptr);
}